// Round 5
// baseline (316.553 us; speedup 1.0000x reference)
//
#include <hip/hip_runtime.h>
#include <hip/hip_bf16.h>

#define SEQ   2048
#define BATCH 2
#define NROWS 4096
#define DM    1024
#define NHEAD 16
#define DH    64
#define QP    512
#define KVP   1024
#define CH    8      // key-tiles (of 64) per flash chunk

typedef unsigned short us;
typedef ushort4 us4;
using bf16x8 = __attribute__((ext_vector_type(8))) __bf16;
using f32x4  = __attribute__((ext_vector_type(4))) float;

__device__ __forceinline__ us f2bf(float f) {
  union { __hip_bfloat16 h; us u; } cv;
  cv.h = __float2bfloat16(f);
  return cv.u;
}
__device__ __forceinline__ float bf2f(us u) {
  union { unsigned int u32; float f; } cv;
  cv.u32 = ((unsigned int)u) << 16;
  return cv.f;
}
__device__ __forceinline__ float loadp(const void* p, long i, int isbf) {
  return isbf ? bf2f(((const us*)p)[i]) : ((const float*)p)[i];
}
__device__ __forceinline__ void async16(const void* g, void* l) {
  __builtin_amdgcn_global_load_lds((__attribute__((address_space(1))) void*)g,
                                   (__attribute__((address_space(3))) void*)l,
                                   16, 0, 0);
}

// ---------------------------------------------------------------- dtype probe
__global__ void detect_dtype(const us* __restrict__ xu, int* __restrict__ flag) {
  __shared__ int red[256];
  const int tid = threadIdx.x;
  int cnt = 0;
  for (int i = tid; i < 4096; i += 256) {
    const int e = (xu[i] >> 7) & 0xff;
    if (e == 0 || (e >= 100 && e <= 134)) cnt++;
  }
  red[tid] = cnt;
  __syncthreads();
  for (int s = 128; s; s >>= 1) {
    if (tid < s) red[tid] += red[tid + s];
    __syncthreads();
  }
  if (tid == 0) *flag = (red[0] >= 3900) ? 1 : 0;
}

// ------------- stage0: weight prep (transpose/cast) + zero Oacc + dual-LN of x
struct TD { const void* in; us* out; int R, C, nt, trans; };

__global__ __launch_bounds__(256) void stage0(
    TD t0, TD t1, TD t2, TD t3, TD t4,
    float4* __restrict__ zp, int n4,                 // zero range (blocks 5120..6143)
    const void* __restrict__ xin,                    // ln_dual (blocks 6144..10239)
    const void* __restrict__ g1, const void* __restrict__ b1,
    const void* __restrict__ g2, const void* __restrict__ b2,
    us* __restrict__ out1, us* __restrict__ out2,
    const int* __restrict__ flag)
{
  __shared__ us tile[32][33];
  __shared__ float red[8];
  __shared__ float musd[2];
  const int tid = threadIdx.x;
  const int isbf = *flag;
  int lin = blockIdx.x;

  if (lin < 5120) {                                  // ---- weight prep
    TD t = t0;
    if (lin >= t.nt) { lin -= t.nt; t = t1;
      if (lin >= t.nt) { lin -= t.nt; t = t2;
        if (lin >= t.nt) { lin -= t.nt; t = t3;
          if (lin >= t.nt) { lin -= t.nt; t = t4; } } } }
    const int ntx = t.C >> 5;
    const int by = lin / ntx, bx = lin - by * ntx;
    const int tx = tid & 31, ty = tid >> 5;
    const long r0 = (long)by * 32, c0 = (long)bx * 32;
    if (t.trans) {
#pragma unroll
      for (int i = 0; i < 32; i += 8)
        tile[ty + i][tx] = isbf ? ((const us*)t.in)[(r0 + ty + i) * t.C + c0 + tx]
                                : f2bf(((const float*)t.in)[(r0 + ty + i) * t.C + c0 + tx]);
      __syncthreads();
#pragma unroll
      for (int i = 0; i < 32; i += 8)
        t.out[(c0 + ty + i) * t.R + r0 + tx] = tile[tx][ty + i];
    } else {
#pragma unroll
      for (int i = 0; i < 32; i += 8)
        t.out[(r0 + ty + i) * t.C + c0 + tx] =
            isbf ? ((const us*)t.in)[(r0 + ty + i) * t.C + c0 + tx]
                 : f2bf(((const float*)t.in)[(r0 + ty + i) * t.C + c0 + tx]);
    }
    return;
  }
  if (lin < 6144) {                                  // ---- zero Oacc/Lacc
    const float4 z = {0.f, 0.f, 0.f, 0.f};
    for (int i = (lin - 5120) * 256 + tid; i < n4; i += 1024 * 256) zp[i] = z;
    return;
  }
  // ---- dual LayerNorm row
  const long row = lin - 6144;
  float v[4];
  float s = 0.f, s2 = 0.f;
#pragma unroll
  for (int i = 0; i < 4; i++) {
    const long c = tid + i * 256;
    const float t = loadp(xin, row * 1024 + c, isbf);
    v[i] = t; s += t; s2 += t * t;
  }
#pragma unroll
  for (int off = 32; off > 0; off >>= 1) {
    s  += __shfl_down(s,  off);
    s2 += __shfl_down(s2, off);
  }
  const int wave = tid >> 6, lane = tid & 63;
  if (lane == 0) { red[wave] = s; red[4 + wave] = s2; }
  __syncthreads();
  if (tid == 0) {
    const float ts = red[0] + red[1] + red[2] + red[3];
    const float t2 = red[4] + red[5] + red[6] + red[7];
    const float mu = ts * (1.f / 1024.f);
    const float var = t2 * (1.f / 1024.f) - mu * mu;
    musd[0] = mu; musd[1] = rsqrtf(var + 1e-5f);
  }
  __syncthreads();
  const float mu = musd[0], rs = musd[1];
#pragma unroll
  for (int i = 0; i < 4; i++) {
    const long c = tid + i * 256;
    const float nrm = (v[i] - mu) * rs;
    out1[row * 1024 + c] = f2bf(nrm * loadp(g1, c, isbf) + loadp(b1, c, isbf));
    out2[row * 1024 + c] = f2bf(nrm * loadp(g2, c, isbf) + loadp(b2, c, isbf));
  }
}

// ------------------------------------------ paired row-LN (bf16 in -> bf16 out)
template<int C>
__device__ __forceinline__ void ln_body(const us* __restrict__ in,
                                        const void* __restrict__ g, const void* __restrict__ b,
                                        us* __restrict__ out, long row, int tid, int isbf) {
  constexpr int NP = C / 256;
  float v[NP];
  float s = 0.f, s2 = 0.f;
#pragma unroll
  for (int i = 0; i < NP; i++) {
    const float t = bf2f(in[row * C + tid + i * 256]);
    v[i] = t; s += t; s2 += t * t;
  }
#pragma unroll
  for (int off = 32; off > 0; off >>= 1) {
    s  += __shfl_down(s,  off);
    s2 += __shfl_down(s2, off);
  }
  __shared__ float red[8];
  __shared__ float musd[2];
  const int wave = tid >> 6, lane = tid & 63;
  if (lane == 0) { red[wave] = s; red[4 + wave] = s2; }
  __syncthreads();
  if (tid == 0) {
    const float ts = red[0] + red[1] + red[2] + red[3];
    const float t2 = red[4] + red[5] + red[6] + red[7];
    const float mu = ts * (1.f / C);
    const float var = t2 * (1.f / C) - mu * mu;
    musd[0] = mu; musd[1] = rsqrtf(var + 1e-5f);
  }
  __syncthreads();
  const float mu = musd[0], rs = musd[1];
#pragma unroll
  for (int i = 0; i < NP; i++) {
    const long c = tid + i * 256;
    out[row * C + c] = f2bf((v[i] - mu) * rs * loadp(g, c, isbf) + loadp(b, c, isbf));
  }
}

__global__ __launch_bounds__(256) void ln_rows_pair(
    const us* __restrict__ inq, const void* __restrict__ qg, const void* __restrict__ qb,
    us* __restrict__ outq,
    const us* __restrict__ inkv, const void* __restrict__ kvg, const void* __restrict__ kvb,
    us* __restrict__ outkv,
    const int* __restrict__ flag)
{
  const int isbf = *flag;
  if (blockIdx.x < NROWS)
    ln_body<512>(inq, qg, qb, outq, blockIdx.x, threadIdx.x, isbf);
  else
    ln_body<1024>(inkv, kvg, kvb, outkv, blockIdx.x - NROWS, threadIdx.x, isbf);
}

// ------------------------------------------------------------------ GEMM C = A @ B
// A [M,K] bf16, Bt [N,K] bf16 (= B^T), C [M,N]. 128x128 tile, BK=64 as two
// 32-wide LDS sub-slices. omode: 0 = fp32 out, 1 = bf16 out, 2 = bf16 iff *flag.
struct GD { const us* A; const us* Bt; void* C; int N, K, nxs; float scale; int omode; };

__global__ __launch_bounds__(256) void gemm_mt(GD g0, GD g1, int nb0,
                                               const int* __restrict__ flag) {
  __shared__ us As[2][128 * 32];
  __shared__ us Bs[2][128 * 32];
  GD g;
  int lin = blockIdx.x;
  if (lin < nb0) g = g0; else { g = g1; lin -= nb0; }
  const int by = lin >> g.nxs;
  const int bx = lin - (by << g.nxs);
  const int N = g.N, K = g.K;

  const int tid  = threadIdx.x;
  const int lane = tid & 63;
  const int wave = tid >> 6;
  const int n16  = lane & 15;
  const int quad = lane >> 4;
  const long m0 = (long)by * 128;
  const long n0 = (long)bx * 128;
  const int wm = (wave >> 1) * 64;
  const int wn = (wave & 1) * 64;

  const f32x4 zero = {0.f, 0.f, 0.f, 0.f};
  f32x4 acc[4][4];
#pragma unroll
  for (int i = 0; i < 4; i++)
#pragma unroll
    for (int j = 0; j < 4; j++) acc[i][j] = zero;

  const int srow = tid >> 2;
  const int scol = (tid & 3) * 8;
  const us* Ag0 = g.A  + (m0 + srow) * K + scol;
  const us* Ag1 = g.A  + (m0 + 64 + srow) * K + scol;
  const us* Bg0 = g.Bt + (n0 + srow) * K + scol;
  const us* Bg1 = g.Bt + (n0 + 64 + srow) * K + scol;
  const int lds_off = srow * 32 + scol;

  for (int k0 = 0; k0 < K; k0 += 64) {
#pragma unroll
    for (int s = 0; s < 2; s++) {
      const int ks = k0 + s * 32;
      async16(Ag0 + ks, As[s] + lds_off);
      async16(Ag1 + ks, As[s] + 2048 + lds_off);
      async16(Bg0 + ks, Bs[s] + lds_off);
      async16(Bg1 + ks, Bs[s] + 2048 + lds_off);
    }
    __syncthreads();
#pragma unroll
    for (int s = 0; s < 2; s++) {
      bf16x8 af[4], bfv[4];
#pragma unroll
      for (int i = 0; i < 4; i++)
        af[i] = *(const bf16x8*)(As[s] + (wm + i * 16 + n16) * 32 + quad * 8);
#pragma unroll
      for (int j = 0; j < 4; j++)
        bfv[j] = *(const bf16x8*)(Bs[s] + (wn + j * 16 + n16) * 32 + quad * 8);
#pragma unroll
      for (int i = 0; i < 4; i++)
#pragma unroll
        for (int j = 0; j < 4; j++)
          acc[i][j] = __builtin_amdgcn_mfma_f32_16x16x32_bf16(af[i], bfv[j], acc[i][j], 0, 0, 0);
    }
    __syncthreads();
  }

  const bool obf = (g.omode == 1) || (g.omode == 2 && *flag != 0);
  float* Cf = (float*)g.C;
  us* Cb = (us*)g.C;
#pragma unroll
  for (int i = 0; i < 4; i++) {
    const long row = m0 + wm + i * 16 + quad * 4;
#pragma unroll
    for (int j = 0; j < 4; j++) {
      const long col = n0 + wn + j * 16 + n16;
#pragma unroll
      for (int r = 0; r < 4; r++) {
        const float v = acc[i][j][r] * g.scale;
        if (obf) Cb[(row + r) * N + col] = f2bf(v);
        else     Cf[(row + r) * N + col] = v;
      }
    }
  }
}

// --------------------------------------------------- causal flash attention (split-K)
// 128-row Q tiles (each wave owns 2 row-frags of 16), 64-key tiles, split into
// chunks of CH key-tiles. Q pre-scaled by log2e/8 -> fixed-m softmax p = 2^s.
// S^T = K·Q^T via swapped MFMA operands; K/V staging amortized over 2x MFMA.
__global__ __launch_bounds__(256, 4) void flash_attn(
    const us* __restrict__ Q, const us* __restrict__ KV,
    float* __restrict__ Oacc, float* __restrict__ Lacc)
{
  __shared__ us Ks[64 * 72];      // [key][dim]
  __shared__ us Vt[64 * 72];      // [dim][key]
  __shared__ us Ps[4][32 * 72];   // per-wave P [row 0..31][key]

  // decode (qt, chunk): qt in 0..15 (128-row tiles), longest-q first
  int lin = blockIdx.x;
  int qt = 15, nc = 0;
  for (; qt >= 0; --qt) { nc = ((2 * qt + 1) >> 3) + 1; if (lin < nc) break; lin -= nc; }
  const int kt0 = lin * CH;
  const int kt1 = min(kt0 + CH, 2 * qt + 2);

  const int h   = blockIdx.y;
  const int bb  = blockIdx.z;
  const int tid = threadIdx.x;
  const int lane = tid & 63;
  const int wave = tid >> 6;
  const int n16 = lane & 15;
  const int quad = lane >> 4;
  const int qbase = qt * 128;
  const long rowQ0 = (long)bb * SEQ;

  bf16x8 aq[2][2];
#pragma unroll
  for (int rg = 0; rg < 2; rg++) {
    const long gq = (rowQ0 + qbase + wave * 32 + rg * 16 + n16) * DM + h * DH;
    aq[rg][0] = *(const bf16x8*)(Q + gq + quad * 8);
    aq[rg][1] = *(const bf16x8*)(Q + gq + 32 + quad * 8);
  }

  const f32x4 zero = {0.f, 0.f, 0.f, 0.f};
  f32x4 oacc[2][4];
#pragma unroll
  for (int rg = 0; rg < 2; rg++)
#pragma unroll
    for (int d = 0; d < 4; d++) oacc[rg][d] = zero;
  float rsum[2] = {0.f, 0.f};

  const int kk_key = tid >> 3;
  const int kk_d8  = (tid & 7) * 8;
  const int vd  = tid & 63;
  const int vkb = (tid >> 6) * 8;

  const us* kgb = KV + (rowQ0 + kk_key) * 2048 + h * DH + kk_d8;
  const us* vgb = KV + (rowQ0 + vkb) * 2048 + KVP + h * DH + vd;

  uint4 kpre0, kpre1;
  us vraw[16];
  auto loadKV = [&](int kt) {
    const us* kg = kgb + (long)kt * (64 * 2048);
    kpre0 = *(const uint4*)kg;
    kpre1 = *(const uint4*)(kg + 32 * 2048);
    const us* vg = vgb + (long)kt * (64 * 2048);
#pragma unroll
    for (int j = 0; j < 8; j++) vraw[j] = vg[j * 2048];
    const us* vg2 = vg + 32 * 2048;
#pragma unroll
    for (int j = 0; j < 8; j++) vraw[8 + j] = vg2[j * 2048];
  };
  loadKV(kt0);

  us* Pw = Ps[wave];
  const int qw = qbase + wave * 32;      // first q-row owned by this wave

  for (int kt = kt0; kt < kt1; kt++) {
    const int kb = kt * 64;
    __syncthreads();
    *(uint4*)(Ks + kk_key * 72 + kk_d8)        = kpre0;
    *(uint4*)(Ks + (kk_key + 32) * 72 + kk_d8) = kpre1;
    {
      uint4 p0, p1;
      p0.x = (unsigned)vraw[0]  | ((unsigned)vraw[1]  << 16);
      p0.y = (unsigned)vraw[2]  | ((unsigned)vraw[3]  << 16);
      p0.z = (unsigned)vraw[4]  | ((unsigned)vraw[5]  << 16);
      p0.w = (unsigned)vraw[6]  | ((unsigned)vraw[7]  << 16);
      p1.x = (unsigned)vraw[8]  | ((unsigned)vraw[9]  << 16);
      p1.y = (unsigned)vraw[10] | ((unsigned)vraw[11] << 16);
      p1.z = (unsigned)vraw[12] | ((unsigned)vraw[13] << 16);
      p1.w = (unsigned)vraw[14] | ((unsigned)vraw[15] << 16);
      *(uint4*)(Vt + vd * 72 + vkb)      = p0;
      *(uint4*)(Vt + vd * 72 + vkb + 32) = p1;
    }
    __syncthreads();
    if (kt + 1 < kt1) loadKV(kt + 1);

    // wave fully above the diagonal? (all its q-rows < all keys of this tile)
    if (kb > qw + 31) continue;

    // S^T = K Q^T for both row-frags; K-frag reads shared.
    f32x4 sv[2][4];
#pragma unroll
    for (int j = 0; j < 4; j++) {
      const bf16x8 ak0 = *(const bf16x8*)(Ks + (j * 16 + n16) * 72 + quad * 8);
      const bf16x8 ak1 = *(const bf16x8*)(Ks + (j * 16 + n16) * 72 + 32 + quad * 8);
#pragma unroll
      for (int rg = 0; rg < 2; rg++) {
        f32x4 s = zero;
        s = __builtin_amdgcn_mfma_f32_16x16x32_bf16(ak0, aq[rg][0], s, 0, 0, 0);
        s = __builtin_amdgcn_mfma_f32_16x16x32_bf16(ak1, aq[rg][1], s, 0, 0, 0);
        sv[rg][j] = s;
      }
    }

    // mask + exp2 + P store (per row-frag; mask only if tile crosses diagonal)
#pragma unroll
    for (int rg = 0; rg < 2; rg++) {
      if (kb + 63 > qw + rg * 16) {          // some key may exceed some q-row
        const int qg = qw + rg * 16 + n16;   // this lane's q row (global)
#pragma unroll
        for (int j = 0; j < 4; j++) {
          const int kl = kb + j * 16 + quad * 4;
#pragma unroll
          for (int r = 0; r < 4; r++)
            sv[rg][j][r] = (kl + r <= qg) ? sv[rg][j][r] : -1e30f;
        }
      }
#pragma unroll
      for (int j = 0; j < 4; j++) {
        const float p0 = __builtin_amdgcn_exp2f(sv[rg][j][0]);
        const float p1 = __builtin_amdgcn_exp2f(sv[rg][j][1]);
        const float p2 = __builtin_amdgcn_exp2f(sv[rg][j][2]);
        const float p3 = __builtin_amdgcn_exp2f(sv[rg][j][3]);
        rsum[rg] += (p0 + p1) + (p2 + p3);
        us4 pk;
        pk.x = f2bf(p0); pk.y = f2bf(p1); pk.z = f2bf(p2); pk.w = f2bf(p3);
        *(us4*)(Pw + (rg * 16 + n16) * 72 + j * 16 + quad * 4) = pk;
      }
    }
    __asm__ volatile("s_waitcnt lgkmcnt(0)" ::: "memory");

    // O += P V  (V-frags shared across row-frags)
#pragma unroll
    for (int kc = 0; kc < 2; kc++) {
      bf16x8 bv[4];
#pragma unroll
      for (int d = 0; d < 4; d++)
        bv[d] = *(const bf16x8*)(Vt + (d * 16 + n16) * 72 + kc * 32 + quad * 8);
#pragma unroll
      for (int rg = 0; rg < 2; rg++) {
        const bf16x8 ap = *(const bf16x8*)(Pw + (rg * 16 + n16) * 72 + kc * 32 + quad * 8);
#pragma unroll
        for (int d = 0; d < 4; d++)
          oacc[rg][d] = __builtin_amdgcn_mfma_f32_16x16x32_bf16(ap, bv[d], oacc[rg][d], 0, 0, 0);
      }
    }
  }

  // epilogue: reduce row-sums across quads, atomically accumulate partials
#pragma unroll
  for (int rg = 0; rg < 2; rg++) {
    float rs = rsum[rg];
    rs += __shfl_xor(rs, 16);
    rs += __shfl_xor(rs, 32);
    const long rw0 = rowQ0 + qbase + wave * 32 + rg * 16;
    if (quad == 0)
      atomicAdd(&Lacc[(rw0 + n16) * NHEAD + h], rs);
#pragma unroll
    for (int r = 0; r < 4; r++) {
      float* dst = Oacc + (rw0 + quad * 4 + r) * DM + h * DH + n16;
#pragma unroll
      for (int d = 0; d < 4; d++)
        atomicAdd(dst + d * 16, oacc[rg][d][r]);
    }
  }
}

// -------------------------------------------- combine: obuf = Oacc / l (bf16)
__global__ __launch_bounds__(256) void flash_combine(
    const float* __restrict__ Oacc, const float* __restrict__ Lacc,
    us* __restrict__ O)
{
  __shared__ float invl[NHEAD];
  const long row = blockIdx.x;
  const int tid = threadIdx.x;
  if (tid < NHEAD) invl[tid] = 1.f / Lacc[row * NHEAD + tid];
  __syncthreads();
#pragma unroll
  for (int i = 0; i < 4; i++) {
    const int col = tid + i * 256;
    O[row * DM + col] = f2bf(Oacc[row * DM + col] * invl[col >> 6]);
  }
}

// ------------------------------------------------------------------------- host
extern "C" void kernel_launch(void* const* d_in, const int* in_sizes, int n_in,
                              void* d_out, int out_size, void* d_ws, size_t ws_size,
                              hipStream_t stream) {
  const void* x      = d_in[0];
  const void* Wdq    = d_in[1];
  const void* Wuq    = d_in[2];
  const void* qg     = d_in[3];
  const void* qb     = d_in[4];
  const void* Wdkv   = d_in[5];
  const void* Wukv   = d_in[6];
  const void* kvg    = d_in[7];
  const void* kvb    = d_in[8];
  const void* preqg  = d_in[9];
  const void* preqb  = d_in[10];
  const void* prekvg = d_in[11];
  const void* prekvb = d_in[12];
  const void* wo     = d_in[13];

  char* ws = (char*)d_ws;
  const long MB = 1 << 20;
  int* flag   = (int*)ws;
  us* wdq_t   = (us*)(ws + 1 * MB);
  us* wuq_t   = (us*)(ws + 2 * MB);
  us* wdkv_t  = (us*)(ws + 3 * MB);
  us* wukv_t  = (us*)(ws + 5 * MB);
  us* wo_c    = (us*)(ws + 9 * MB);
  us* xq      = (us*)(ws + 11 * MB);                       // 8 MB
  us* xkv     = (us*)(ws + 19 * MB);                       // 8 MB
  float* Oacc = (float*)(ws + 27 * MB);                    // 16 MB (zeroed in stage0)
  float* Lacc = (float*)(ws + 43 * MB);                    // 256 KB
  us* obuf    = (us*)(ws + 43 * MB + 256 * 1024);          // 8 MB
  us* tq_bf   = obuf;                                      // overlay: dead before combine
  us* cq      = (us*)(ws + 43 * MB + 256 * 1024 + 8 * MB); // 4 MB
  us* qbuf    = (us*)(ws + 43 * MB + 256 * 1024 + 12 * MB);// 8 MB
  us* tkv_bf  = qbuf;                                      // overlay: dead before up-GEMM
  us* ckv     = (us*)(ws + 43 * MB + 256 * 1024 + 20 * MB);// 8 MB
  us* kv      = (us*)(ws + 43 * MB + 256 * 1024 + 28 * MB);// 16 MB -> ~87.25 MB total

  detect_dtype<<<1, 256, 0, stream>>>((const us*)x, flag);

  // stage0: weights (5120 blocks) + zero Oacc/Lacc (1024) + ln_dual (4096)
  {
    TD t0 = { Wdq,  wdq_t,  1024,  512,  512, 1 };
    TD t1 = { Wuq,  wuq_t,   512, 1024,  512, 1 };
    TD t2 = { Wdkv, wdkv_t, 1024, 1024, 1024, 1 };
    TD t3 = { Wukv, wukv_t, 1024, 2048, 2048, 1 };
    TD t4 = { wo,   wo_c,   1024, 1024, 1024, 0 };
    const int n4 = (16 * 1024 * 1024 + 256 * 1024) / 16;
    stage0<<<10240, 256, 0, stream>>>(t0, t1, t2, t3, t4,
                                      (float4*)Oacc, n4,
                                      x, preqg, preqb, prekvg, prekvb, xq, xkv, flag);
  }

  // down-projection pair (bf16 out)
  {
    GD g0 = { xq,  wdq_t,  tq_bf,   512, 1024, 2, 1.f, 1 };
    GD g1 = { xkv, wdkv_t, tkv_bf, 1024, 1024, 3, 1.f, 1 };
    gemm_mt<<<384, 256, 0, stream>>>(g0, g1, 128, flag);
  }

  ln_rows_pair<<<2 * NROWS, 256, 0, stream>>>(tq_bf, qg, qb, cq, tkv_bf, kvg, kvb, ckv, flag);

  // up-projection pair: Q scale = (1/8)*log2e for exp2-softmax
  {
    GD g0 = { cq,  wuq_t,  qbuf, 1024,  512, 3, 0.125f * 1.44269504f, 1 };
    GD g1 = { ckv, wukv_t, kv,   2048, 1024, 4, 1.f, 1 };
    gemm_mt<<<768, 256, 0, stream>>>(g0, g1, 256, flag);
  }

  // flash: grid.x = sum over qt=0..15 of ceil((2qt+2)/CH) = 40
  flash_attn<<<dim3(40, NHEAD, BATCH), 256, 0, stream>>>(qbuf, kv, Oacc, Lacc);
  flash_combine<<<NROWS, 256, 0, stream>>>(Oacc, Lacc, obuf);

  // out = O @ wo^T
  {
    GD g0 = { obuf, wo_c, d_out, 1024, 1024, 3, 1.f, 2 };
    gemm_mt<<<256, 256, 0, stream>>>(g0, g0, 256, flag);
  }
}

// Round 6
// 282.606 us; speedup vs baseline: 1.1201x; 1.1201x over previous
//
#include <hip/hip_runtime.h>
#include <hip/hip_bf16.h>

#define SEQ   2048
#define BATCH 2
#define NROWS 4096
#define DM    1024
#define NHEAD 16
#define DH    64
#define QP    512
#define KVP   1024
#define CH    8      // key-tiles (of 64) per flash chunk

typedef unsigned short us;
typedef ushort4 us4;
using bf16x8 = __attribute__((ext_vector_type(8))) __bf16;
using f32x4  = __attribute__((ext_vector_type(4))) float;

__device__ __forceinline__ us f2bf(float f) {
  union { __hip_bfloat16 h; us u; } cv;
  cv.h = __float2bfloat16(f);
  return cv.u;
}
__device__ __forceinline__ float bf2f(us u) {
  union { unsigned int u32; float f; } cv;
  cv.u32 = ((unsigned int)u) << 16;
  return cv.f;
}
__device__ __forceinline__ float loadp(const void* p, long i, int isbf) {
  return isbf ? bf2f(((const us*)p)[i]) : ((const float*)p)[i];
}
__device__ __forceinline__ void async16(const void* g, void* l) {
  __builtin_amdgcn_global_load_lds((__attribute__((address_space(1))) void*)g,
                                   (__attribute__((address_space(3))) void*)l,
                                   16, 0, 0);
}

// ---------------------------------------------------------------- dtype probe
__global__ void detect_dtype(const us* __restrict__ xu, int* __restrict__ flag) {
  __shared__ int red[256];
  const int tid = threadIdx.x;
  int cnt = 0;
  for (int i = tid; i < 4096; i += 256) {
    const int e = (xu[i] >> 7) & 0xff;
    if (e == 0 || (e >= 100 && e <= 134)) cnt++;
  }
  red[tid] = cnt;
  __syncthreads();
  for (int s = 128; s; s >>= 1) {
    if (tid < s) red[tid] += red[tid + s];
    __syncthreads();
  }
  if (tid == 0) *flag = (red[0] >= 3900) ? 1 : 0;
}

// ------------- stage0: weight prep (transpose/cast) + zero Oacc + dual-LN of x
struct TD { const void* in; us* out; int R, C, nt, trans; };

__global__ __launch_bounds__(256) void stage0(
    TD t0, TD t1, TD t2, TD t3, TD t4,
    float4* __restrict__ zp, int n4,                 // zero range (blocks 5120..6143)
    const void* __restrict__ xin,                    // ln_dual (blocks 6144..10239)
    const void* __restrict__ g1, const void* __restrict__ b1,
    const void* __restrict__ g2, const void* __restrict__ b2,
    us* __restrict__ out1, us* __restrict__ out2,
    const int* __restrict__ flag)
{
  __shared__ us tile[32][33];
  __shared__ float red[8];
  __shared__ float musd[2];
  const int tid = threadIdx.x;
  const int isbf = *flag;
  int lin = blockIdx.x;

  if (lin < 5120) {                                  // ---- weight prep
    TD t = t0;
    if (lin >= t.nt) { lin -= t.nt; t = t1;
      if (lin >= t.nt) { lin -= t.nt; t = t2;
        if (lin >= t.nt) { lin -= t.nt; t = t3;
          if (lin >= t.nt) { lin -= t.nt; t = t4; } } } }
    const int ntx = t.C >> 5;
    const int by = lin / ntx, bx = lin - by * ntx;
    const int tx = tid & 31, ty = tid >> 5;
    const long r0 = (long)by * 32, c0 = (long)bx * 32;
    if (t.trans) {
#pragma unroll
      for (int i = 0; i < 32; i += 8)
        tile[ty + i][tx] = isbf ? ((const us*)t.in)[(r0 + ty + i) * t.C + c0 + tx]
                                : f2bf(((const float*)t.in)[(r0 + ty + i) * t.C + c0 + tx]);
      __syncthreads();
#pragma unroll
      for (int i = 0; i < 32; i += 8)
        t.out[(c0 + ty + i) * t.R + r0 + tx] = tile[tx][ty + i];
    } else {
#pragma unroll
      for (int i = 0; i < 32; i += 8)
        t.out[(r0 + ty + i) * t.C + c0 + tx] =
            isbf ? ((const us*)t.in)[(r0 + ty + i) * t.C + c0 + tx]
                 : f2bf(((const float*)t.in)[(r0 + ty + i) * t.C + c0 + tx]);
    }
    return;
  }
  if (lin < 6144) {                                  // ---- zero Oacc/Lacc
    const float4 z = {0.f, 0.f, 0.f, 0.f};
    for (int i = (lin - 5120) * 256 + tid; i < n4; i += 1024 * 256) zp[i] = z;
    return;
  }
  // ---- dual LayerNorm row
  const long row = lin - 6144;
  float v[4];
  float s = 0.f, s2 = 0.f;
#pragma unroll
  for (int i = 0; i < 4; i++) {
    const long c = tid + i * 256;
    const float t = loadp(xin, row * 1024 + c, isbf);
    v[i] = t; s += t; s2 += t * t;
  }
#pragma unroll
  for (int off = 32; off > 0; off >>= 1) {
    s  += __shfl_down(s,  off);
    s2 += __shfl_down(s2, off);
  }
  const int wave = tid >> 6, lane = tid & 63;
  if (lane == 0) { red[wave] = s; red[4 + wave] = s2; }
  __syncthreads();
  if (tid == 0) {
    const float ts = red[0] + red[1] + red[2] + red[3];
    const float t2 = red[4] + red[5] + red[6] + red[7];
    const float mu = ts * (1.f / 1024.f);
    const float var = t2 * (1.f / 1024.f) - mu * mu;
    musd[0] = mu; musd[1] = rsqrtf(var + 1e-5f);
  }
  __syncthreads();
  const float mu = musd[0], rs = musd[1];
#pragma unroll
  for (int i = 0; i < 4; i++) {
    const long c = tid + i * 256;
    const float nrm = (v[i] - mu) * rs;
    out1[row * 1024 + c] = f2bf(nrm * loadp(g1, c, isbf) + loadp(b1, c, isbf));
    out2[row * 1024 + c] = f2bf(nrm * loadp(g2, c, isbf) + loadp(b2, c, isbf));
  }
}

// ------------------------------------------ paired row-LN (bf16 in -> bf16 out)
template<int C>
__device__ __forceinline__ void ln_body(const us* __restrict__ in,
                                        const void* __restrict__ g, const void* __restrict__ b,
                                        us* __restrict__ out, long row, int tid, int isbf) {
  constexpr int NP = C / 256;
  float v[NP];
  float s = 0.f, s2 = 0.f;
#pragma unroll
  for (int i = 0; i < NP; i++) {
    const float t = bf2f(in[row * C + tid + i * 256]);
    v[i] = t; s += t; s2 += t * t;
  }
#pragma unroll
  for (int off = 32; off > 0; off >>= 1) {
    s  += __shfl_down(s,  off);
    s2 += __shfl_down(s2, off);
  }
  __shared__ float red[8];
  __shared__ float musd[2];
  const int wave = tid >> 6, lane = tid & 63;
  if (lane == 0) { red[wave] = s; red[4 + wave] = s2; }
  __syncthreads();
  if (tid == 0) {
    const float ts = red[0] + red[1] + red[2] + red[3];
    const float t2 = red[4] + red[5] + red[6] + red[7];
    const float mu = ts * (1.f / C);
    const float var = t2 * (1.f / C) - mu * mu;
    musd[0] = mu; musd[1] = rsqrtf(var + 1e-5f);
  }
  __syncthreads();
  const float mu = musd[0], rs = musd[1];
#pragma unroll
  for (int i = 0; i < NP; i++) {
    const long c = tid + i * 256;
    out[row * C + c] = f2bf((v[i] - mu) * rs * loadp(g, c, isbf) + loadp(b, c, isbf));
  }
}

__global__ __launch_bounds__(256) void ln_rows_pair(
    const us* __restrict__ inq, const void* __restrict__ qg, const void* __restrict__ qb,
    us* __restrict__ outq,
    const us* __restrict__ inkv, const void* __restrict__ kvg, const void* __restrict__ kvb,
    us* __restrict__ outkv,
    const int* __restrict__ flag)
{
  const int isbf = *flag;
  if (blockIdx.x < NROWS)
    ln_body<512>(inq, qg, qb, outq, blockIdx.x, threadIdx.x, isbf);
  else
    ln_body<1024>(inkv, kvg, kvb, outkv, blockIdx.x - NROWS, threadIdx.x, isbf);
}

// ------------------------------------------------------------------ GEMM C = A @ B
// A [M,K] bf16, Bt [N,K] bf16 (= B^T), C [M,N]. 128x128 tile, BK=64 as two
// 32-wide LDS sub-slices. omode: 0 = fp32 out, 1 = bf16 out, 2 = bf16 iff *flag.
struct GD { const us* A; const us* Bt; void* C; int N, K, nxs; float scale; int omode; };

__global__ __launch_bounds__(256) void gemm_mt(GD g0, GD g1, int nb0,
                                               const int* __restrict__ flag) {
  __shared__ us As[2][128 * 32];
  __shared__ us Bs[2][128 * 32];
  GD g;
  int lin = blockIdx.x;
  if (lin < nb0) g = g0; else { g = g1; lin -= nb0; }
  const int by = lin >> g.nxs;
  const int bx = lin - (by << g.nxs);
  const int N = g.N, K = g.K;

  const int tid  = threadIdx.x;
  const int lane = tid & 63;
  const int wave = tid >> 6;
  const int n16  = lane & 15;
  const int quad = lane >> 4;
  const long m0 = (long)by * 128;
  const long n0 = (long)bx * 128;
  const int wm = (wave >> 1) * 64;
  const int wn = (wave & 1) * 64;

  const f32x4 zero = {0.f, 0.f, 0.f, 0.f};
  f32x4 acc[4][4];
#pragma unroll
  for (int i = 0; i < 4; i++)
#pragma unroll
    for (int j = 0; j < 4; j++) acc[i][j] = zero;

  const int srow = tid >> 2;
  const int scol = (tid & 3) * 8;
  const us* Ag0 = g.A  + (m0 + srow) * K + scol;
  const us* Ag1 = g.A  + (m0 + 64 + srow) * K + scol;
  const us* Bg0 = g.Bt + (n0 + srow) * K + scol;
  const us* Bg1 = g.Bt + (n0 + 64 + srow) * K + scol;
  const int lds_off = srow * 32 + scol;

  for (int k0 = 0; k0 < K; k0 += 64) {
#pragma unroll
    for (int s = 0; s < 2; s++) {
      const int ks = k0 + s * 32;
      async16(Ag0 + ks, As[s] + lds_off);
      async16(Ag1 + ks, As[s] + 2048 + lds_off);
      async16(Bg0 + ks, Bs[s] + lds_off);
      async16(Bg1 + ks, Bs[s] + 2048 + lds_off);
    }
    __syncthreads();
#pragma unroll
    for (int s = 0; s < 2; s++) {
      bf16x8 af[4], bfv[4];
#pragma unroll
      for (int i = 0; i < 4; i++)
        af[i] = *(const bf16x8*)(As[s] + (wm + i * 16 + n16) * 32 + quad * 8);
#pragma unroll
      for (int j = 0; j < 4; j++)
        bfv[j] = *(const bf16x8*)(Bs[s] + (wn + j * 16 + n16) * 32 + quad * 8);
#pragma unroll
      for (int i = 0; i < 4; i++)
#pragma unroll
        for (int j = 0; j < 4; j++)
          acc[i][j] = __builtin_amdgcn_mfma_f32_16x16x32_bf16(af[i], bfv[j], acc[i][j], 0, 0, 0);
    }
    __syncthreads();
  }

  const bool obf = (g.omode == 1) || (g.omode == 2 && *flag != 0);
  float* Cf = (float*)g.C;
  us* Cb = (us*)g.C;
#pragma unroll
  for (int i = 0; i < 4; i++) {
    const long row = m0 + wm + i * 16 + quad * 4;
#pragma unroll
    for (int j = 0; j < 4; j++) {
      const long col = n0 + wn + j * 16 + n16;
#pragma unroll
      for (int r = 0; r < 4; r++) {
        const float v = acc[i][j][r] * g.scale;
        if (obf) Cb[(row + r) * N + col] = f2bf(v);
        else     Cf[(row + r) * N + col] = v;
      }
    }
  }
}

// --------------------------------------------------- causal flash attention (split-K)
// 128-row Q tiles (each wave owns 2 row-frags of 16), 64-key tiles, chunks of
// CH key-tiles. Q pre-scaled by log2e/8 -> fixed-m softmax p = 2^s.
// S^T = K·Q^T via swapped MFMA operands. NO min-occupancy bound: R5's
// __launch_bounds__(256,4) forced VGPR=64 -> scratch spills (WRITE_SIZE 2.4x,
// VALUBusy 13%). LDS 36.9KB caps residency at 4 blocks/CU; VGPR <=128 keeps it.
__global__ __launch_bounds__(256) void flash_attn(
    const us* __restrict__ Q, const us* __restrict__ KV,
    float* __restrict__ Oacc, float* __restrict__ Lacc)
{
  __shared__ us Ks[64 * 72];      // [key][dim]
  __shared__ us Vt[64 * 72];      // [dim][key]
  __shared__ us Ps[4][32 * 72];   // per-wave P [row 0..31][key]

  // decode (qt, chunk): qt in 0..15 (128-row tiles), longest-q first
  int lin = blockIdx.x;
  int qt = 15, nc = 0;
  for (; qt >= 0; --qt) { nc = ((2 * qt + 1) >> 3) + 1; if (lin < nc) break; lin -= nc; }
  const int kt0 = lin * CH;
  const int kt1 = min(kt0 + CH, 2 * qt + 2);

  const int h   = blockIdx.y;
  const int bb  = blockIdx.z;
  const int tid = threadIdx.x;
  const int lane = tid & 63;
  const int wave = tid >> 6;
  const int n16 = lane & 15;
  const int quad = lane >> 4;
  const int qbase = qt * 128;
  const long rowQ0 = (long)bb * SEQ;

  bf16x8 aq[2][2];
#pragma unroll
  for (int rg = 0; rg < 2; rg++) {
    const long gq = (rowQ0 + qbase + wave * 32 + rg * 16 + n16) * DM + h * DH;
    aq[rg][0] = *(const bf16x8*)(Q + gq + quad * 8);
    aq[rg][1] = *(const bf16x8*)(Q + gq + 32 + quad * 8);
  }

  const f32x4 zero = {0.f, 0.f, 0.f, 0.f};
  f32x4 oacc[2][4];
#pragma unroll
  for (int rg = 0; rg < 2; rg++)
#pragma unroll
    for (int d = 0; d < 4; d++) oacc[rg][d] = zero;
  float rsum[2] = {0.f, 0.f};

  const int kk_key = tid >> 3;
  const int kk_d8  = (tid & 7) * 8;
  const int vd  = tid & 63;
  const int vkb = (tid >> 6) * 8;

  const us* kgb = KV + (rowQ0 + kk_key) * 2048 + h * DH + kk_d8;
  const us* vgb = KV + (rowQ0 + vkb) * 2048 + KVP + h * DH + vd;

  uint4 kpre0, kpre1;
  us vraw[16];
  auto loadKV = [&](int kt) {
    const us* kg = kgb + (long)kt * (64 * 2048);
    kpre0 = *(const uint4*)kg;
    kpre1 = *(const uint4*)(kg + 32 * 2048);
    const us* vg = vgb + (long)kt * (64 * 2048);
#pragma unroll
    for (int j = 0; j < 8; j++) vraw[j] = vg[j * 2048];
    const us* vg2 = vg + 32 * 2048;
#pragma unroll
    for (int j = 0; j < 8; j++) vraw[8 + j] = vg2[j * 2048];
  };
  loadKV(kt0);

  us* Pw = Ps[wave];
  const int qw = qbase + wave * 32;      // first q-row owned by this wave

  for (int kt = kt0; kt < kt1; kt++) {
    const int kb = kt * 64;
    __syncthreads();
    *(uint4*)(Ks + kk_key * 72 + kk_d8)        = kpre0;
    *(uint4*)(Ks + (kk_key + 32) * 72 + kk_d8) = kpre1;
    {
      uint4 p0, p1;
      p0.x = (unsigned)vraw[0]  | ((unsigned)vraw[1]  << 16);
      p0.y = (unsigned)vraw[2]  | ((unsigned)vraw[3]  << 16);
      p0.z = (unsigned)vraw[4]  | ((unsigned)vraw[5]  << 16);
      p0.w = (unsigned)vraw[6]  | ((unsigned)vraw[7]  << 16);
      p1.x = (unsigned)vraw[8]  | ((unsigned)vraw[9]  << 16);
      p1.y = (unsigned)vraw[10] | ((unsigned)vraw[11] << 16);
      p1.z = (unsigned)vraw[12] | ((unsigned)vraw[13] << 16);
      p1.w = (unsigned)vraw[14] | ((unsigned)vraw[15] << 16);
      *(uint4*)(Vt + vd * 72 + vkb)      = p0;
      *(uint4*)(Vt + vd * 72 + vkb + 32) = p1;
    }
    __syncthreads();
    if (kt + 1 < kt1) loadKV(kt + 1);

    // wave fully above the diagonal? (all its q-rows < all keys of this tile)
    if (kb > qw + 31) continue;

    // S^T = K Q^T for both row-frags; K-frag reads shared.
    f32x4 sv[2][4];
#pragma unroll
    for (int j = 0; j < 4; j++) {
      const bf16x8 ak0 = *(const bf16x8*)(Ks + (j * 16 + n16) * 72 + quad * 8);
      const bf16x8 ak1 = *(const bf16x8*)(Ks + (j * 16 + n16) * 72 + 32 + quad * 8);
#pragma unroll
      for (int rg = 0; rg < 2; rg++) {
        f32x4 s = zero;
        s = __builtin_amdgcn_mfma_f32_16x16x32_bf16(ak0, aq[rg][0], s, 0, 0, 0);
        s = __builtin_amdgcn_mfma_f32_16x16x32_bf16(ak1, aq[rg][1], s, 0, 0, 0);
        sv[rg][j] = s;
      }
    }

    // mask + exp2 + P store (per row-frag; mask only if tile crosses diagonal)
#pragma unroll
    for (int rg = 0; rg < 2; rg++) {
      if (kb + 63 > qw + rg * 16) {
        const int qg = qw + rg * 16 + n16;   // this lane's q row (global)
#pragma unroll
        for (int j = 0; j < 4; j++) {
          const int kl = kb + j * 16 + quad * 4;
#pragma unroll
          for (int r = 0; r < 4; r++)
            sv[rg][j][r] = (kl + r <= qg) ? sv[rg][j][r] : -1e30f;
        }
      }
#pragma unroll
      for (int j = 0; j < 4; j++) {
        const float p0 = __builtin_amdgcn_exp2f(sv[rg][j][0]);
        const float p1 = __builtin_amdgcn_exp2f(sv[rg][j][1]);
        const float p2 = __builtin_amdgcn_exp2f(sv[rg][j][2]);
        const float p3 = __builtin_amdgcn_exp2f(sv[rg][j][3]);
        rsum[rg] += (p0 + p1) + (p2 + p3);
        us4 pk;
        pk.x = f2bf(p0); pk.y = f2bf(p1); pk.z = f2bf(p2); pk.w = f2bf(p3);
        *(us4*)(Pw + (rg * 16 + n16) * 72 + j * 16 + quad * 4) = pk;
      }
    }
    __asm__ volatile("s_waitcnt lgkmcnt(0)" ::: "memory");

    // O += P V  (per row-frag; V-frags re-read to shorten live ranges)
#pragma unroll
    for (int rg = 0; rg < 2; rg++)
#pragma unroll
      for (int kc = 0; kc < 2; kc++) {
        const bf16x8 ap = *(const bf16x8*)(Pw + (rg * 16 + n16) * 72 + kc * 32 + quad * 8);
#pragma unroll
        for (int d = 0; d < 4; d++) {
          const bf16x8 bv = *(const bf16x8*)(Vt + (d * 16 + n16) * 72 + kc * 32 + quad * 8);
          oacc[rg][d] = __builtin_amdgcn_mfma_f32_16x16x32_bf16(ap, bv, oacc[rg][d], 0, 0, 0);
        }
      }
  }

  // epilogue: reduce row-sums across quads, atomically accumulate partials
#pragma unroll
  for (int rg = 0; rg < 2; rg++) {
    float rs = rsum[rg];
    rs += __shfl_xor(rs, 16);
    rs += __shfl_xor(rs, 32);
    const long rw0 = rowQ0 + qbase + wave * 32 + rg * 16;
    if (quad == 0)
      atomicAdd(&Lacc[(rw0 + n16) * NHEAD + h], rs);
#pragma unroll
    for (int r = 0; r < 4; r++) {
      float* dst = Oacc + (rw0 + quad * 4 + r) * DM + h * DH + n16;
#pragma unroll
      for (int d = 0; d < 4; d++)
        atomicAdd(dst + d * 16, oacc[rg][d][r]);
    }
  }
}

// -------------------------------------------- combine: obuf = Oacc / l (bf16)
__global__ __launch_bounds__(256) void flash_combine(
    const float* __restrict__ Oacc, const float* __restrict__ Lacc,
    us* __restrict__ O)
{
  __shared__ float invl[NHEAD];
  const long row = blockIdx.x;
  const int tid = threadIdx.x;
  if (tid < NHEAD) invl[tid] = 1.f / Lacc[row * NHEAD + tid];
  __syncthreads();
#pragma unroll
  for (int i = 0; i < 4; i++) {
    const int col = tid + i * 256;
    O[row * DM + col] = f2bf(Oacc[row * DM + col] * invl[col >> 6]);
  }
}

// ------------------------------------------------------------------------- host
extern "C" void kernel_launch(void* const* d_in, const int* in_sizes, int n_in,
                              void* d_out, int out_size, void* d_ws, size_t ws_size,
                              hipStream_t stream) {
  const void* x      = d_in[0];
  const void* Wdq    = d_in[1];
  const void* Wuq    = d_in[2];
  const void* qg     = d_in[3];
  const void* qb     = d_in[4];
  const void* Wdkv   = d_in[5];
  const void* Wukv   = d_in[6];
  const void* kvg    = d_in[7];
  const void* kvb    = d_in[8];
  const void* preqg  = d_in[9];
  const void* preqb  = d_in[10];
  const void* prekvg = d_in[11];
  const void* prekvb = d_in[12];
  const void* wo     = d_in[13];

  char* ws = (char*)d_ws;
  const long MB = 1 << 20;
  int* flag   = (int*)ws;
  us* wdq_t   = (us*)(ws + 1 * MB);
  us* wuq_t   = (us*)(ws + 2 * MB);
  us* wdkv_t  = (us*)(ws + 3 * MB);
  us* wukv_t  = (us*)(ws + 5 * MB);
  us* wo_c    = (us*)(ws + 9 * MB);
  us* xq      = (us*)(ws + 11 * MB);                       // 8 MB
  us* xkv     = (us*)(ws + 19 * MB);                       // 8 MB
  float* Oacc = (float*)(ws + 27 * MB);                    // 16 MB (zeroed in stage0)
  float* Lacc = (float*)(ws + 43 * MB);                    // 256 KB
  us* obuf    = (us*)(ws + 43 * MB + 256 * 1024);          // 8 MB
  us* tq_bf   = obuf;                                      // overlay: dead before combine
  us* cq      = (us*)(ws + 43 * MB + 256 * 1024 + 8 * MB); // 4 MB
  us* qbuf    = (us*)(ws + 43 * MB + 256 * 1024 + 12 * MB);// 8 MB
  us* tkv_bf  = qbuf;                                      // overlay: dead before up-GEMM
  us* ckv     = (us*)(ws + 43 * MB + 256 * 1024 + 20 * MB);// 8 MB
  us* kv      = (us*)(ws + 43 * MB + 256 * 1024 + 28 * MB);// 16 MB -> ~87.25 MB total

  detect_dtype<<<1, 256, 0, stream>>>((const us*)x, flag);

  // stage0: weights (5120 blocks) + zero Oacc/Lacc (1024) + ln_dual (4096)
  {
    TD t0 = { Wdq,  wdq_t,  1024,  512,  512, 1 };
    TD t1 = { Wuq,  wuq_t,   512, 1024,  512, 1 };
    TD t2 = { Wdkv, wdkv_t, 1024, 1024, 1024, 1 };
    TD t3 = { Wukv, wukv_t, 1024, 2048, 2048, 1 };
    TD t4 = { wo,   wo_c,   1024, 1024, 1024, 0 };
    const int n4 = (16 * 1024 * 1024 + 256 * 1024) / 16;
    stage0<<<10240, 256, 0, stream>>>(t0, t1, t2, t3, t4,
                                      (float4*)Oacc, n4,
                                      x, preqg, preqb, prekvg, prekvb, xq, xkv, flag);
  }

  // down-projection pair (bf16 out)
  {
    GD g0 = { xq,  wdq_t,  tq_bf,   512, 1024, 2, 1.f, 1 };
    GD g1 = { xkv, wdkv_t, tkv_bf, 1024, 1024, 3, 1.f, 1 };
    gemm_mt<<<384, 256, 0, stream>>>(g0, g1, 128, flag);
  }

  ln_rows_pair<<<2 * NROWS, 256, 0, stream>>>(tq_bf, qg, qb, cq, tkv_bf, kvg, kvb, ckv, flag);

  // up-projection pair: Q scale = (1/8)*log2e for exp2-softmax
  {
    GD g0 = { cq,  wuq_t,  qbuf, 1024,  512, 3, 0.125f * 1.44269504f, 1 };
    GD g1 = { ckv, wukv_t, kv,   2048, 1024, 4, 1.f, 1 };
    gemm_mt<<<768, 256, 0, stream>>>(g0, g1, 256, flag);
  }

  // flash: grid.x = sum over qt=0..15 of ceil((2qt+2)/CH) = 40
  flash_attn<<<dim3(40, NHEAD, BATCH), 256, 0, stream>>>(qbuf, kv, Oacc, Lacc);
  flash_combine<<<NROWS, 256, 0, stream>>>(Oacc, Lacc, obuf);

  // out = O @ wo^T
  {
    GD g0 = { obuf, wo_c, d_out, 1024, 1024, 3, 1.f, 2 };
    gemm_mt<<<256, 256, 0, stream>>>(g0, g0, 256, flag);
  }
}